// Round 3
// baseline (138.570 us; speedup 1.0000x reference)
//
#include <hip/hip_runtime.h>
#include <hip/hip_bf16.h>
#include <math.h>

using bf16x8 = __attribute__((ext_vector_type(8))) __bf16;
using bf16x4 = __attribute__((ext_vector_type(4))) __bf16;
using f32x4  = __attribute__((ext_vector_type(4))) float;

static constexpr int SEQ = 4096;
static constexpr int DIM = 64;
static constexpr int NB  = 4;

// ---------------------------------------------------------------------------
// Kernel 0: cast+transpose W -> WT[slot][out][d] bf16.
// ---------------------------------------------------------------------------
__global__ __launch_bounds__(256)
void wprep_kernel(const float* __restrict__ w, __bf16* __restrict__ WT)
{
    const int idx = (int)blockIdx.x * 256 + (int)threadIdx.x;  // < 3*64*64
    const int s = idx >> 12;
    const int o = (idx >> 6) & 63;
    const int d = idx & 63;
    WT[idx] = (__bf16)w[(s * DIM + d) * DIM + o];
}

// ---------------------------------------------------------------------------
// Kernel 1: fused pos-embed + QKV projection. 1 wave = 16 rows x 64 cols of
// one slot. grid = (B*S/16, 3). Q pre-scaled by 0.125. V stored k-permuted:
// within each 64-k block, element kl = 32h + 16b4 + 4g + r lives at
// pos = 32h + 8g + 4b4 + r  => attention V-frags are single 16B loads.
// A/B frag k-pattern (lane g, elem e) <- k = 32h + 8g + e, identical for A
// and B => correct for any HW k-permutation.
// ---------------------------------------------------------------------------
__global__ __launch_bounds__(64)
void qkv_prep_kernel(const float* __restrict__ x, const __bf16* __restrict__ WT,
                     __bf16* __restrict__ Qb, __bf16* __restrict__ Kb,
                     __bf16* __restrict__ VTb)
{
    const int lane = (int)threadIdx.x;
    const int g  = lane >> 4;
    const int cl = lane & 15;
    const int rowbase = (int)blockIdx.x * 16;   // in [0, B*S)
    const int slot    = (int)blockIdx.y;        // 0=Q 1=K 2=V

    // B fragments: wf[nt][h][e] = W[32h+8g+e][nt*16+cl]  (one 16B load each)
    const __bf16* wt = WT + slot * DIM * DIM;
    bf16x8 wf[4][2];
#pragma unroll
    for (int nt = 0; nt < 4; ++nt)
#pragma unroll
        for (int h = 0; h < 2; ++h)
            wf[nt][h] = *reinterpret_cast<const bf16x8*>(wt + (nt*16 + cl) * DIM + 32*h + 8*g);

    // A fragments: x' = x + pos_embed, rounded to bf16. One row per lane (cl).
    const int row  = rowbase + cl;
    const int spos = row & (SEQ - 1);
    bf16x8 xa[2];
#pragma unroll
    for (int h = 0; h < 2; ++h) {
        const float* xp = x + (long)row * DIM + 32*h + 8*g;
        f32x4 x0 = *reinterpret_cast<const f32x4*>(xp);
        f32x4 x1 = *reinterpret_cast<const f32x4*>(xp + 4);
        bf16x8 v;
#pragma unroll
        for (int e = 0; e < 8; ++e) {
            const int c = 32*h + 8*g + e;
            const float invf = exp2f(-13.287712379549449f * ((float)c * 0.03125f));
            const float pe   = __sinf((float)spos * invf);
            const float xv   = (e < 4) ? x0[e] : x1[e - 4];
            v[e] = (__bf16)(xv + pe);
        }
        xa[h] = v;
    }

    f32x4 acc[4];
#pragma unroll
    for (int nt = 0; nt < 4; ++nt) acc[nt] = (f32x4){0.f, 0.f, 0.f, 0.f};
#pragma unroll
    for (int nt = 0; nt < 4; ++nt) {
        acc[nt] = __builtin_amdgcn_mfma_f32_16x16x32_bf16(xa[0], wf[nt][0], acc[nt], 0, 0, 0);
        acc[nt] = __builtin_amdgcn_mfma_f32_16x16x32_bf16(xa[1], wf[nt][1], acc[nt], 0, 0, 0);
    }

    // C/D layout (HW-verified): lane l, reg r -> row (l>>4)*4+r, col l&15.
    if (slot < 2) {
        __bf16* dst = (slot == 0) ? Qb : Kb;
        const float scale = (slot == 0) ? 0.125f : 1.0f;
#pragma unroll
        for (int nt = 0; nt < 4; ++nt)
#pragma unroll
            for (int r = 0; r < 4; ++r) {
                const int ro = rowbase + 4*g + r;
                dst[(long)ro * DIM + nt*16 + cl] = (__bf16)(acc[nt][r] * scale);
            }
    } else {
        const int bi   = rowbase >> 12;
        const int sp   = rowbase & (SEQ - 1);
        const int kblk = sp & ~63;
        const int pos0 = 32 * ((rowbase >> 5) & 1) + 8*g + 4 * ((rowbase >> 4) & 1);
#pragma unroll
        for (int nt = 0; nt < 4; ++nt) {
            bf16x4 pk;
#pragma unroll
            for (int r = 0; r < 4; ++r) pk[r] = (__bf16)acc[nt][r];
            *reinterpret_cast<bf16x4*>(VTb + ((long)bi*DIM + nt*16 + cl) * SEQ + kblk + pos0) = pk;
        }
    }
}

// ---------------------------------------------------------------------------
// Kernel 2: flash attention, 8-way intra-block split-K.
// Block = 8 waves (512 thr); wave w handles k in [w*512, (w+1)*512) for the
// SAME 16 q-rows. 1D grid of 1024 blocks, XCD-batch swizzled so each XCD
// serves one batch (K+V working set 1 MB -> L2 resident).
// __launch_bounds__(512, 8) forces VGPR<=64 -> 4 blocks/CU = 32 waves/CU.
// Partials (m, l, acc) merged through LDS (flash-decode combine).
// ---------------------------------------------------------------------------
__global__ __launch_bounds__(512, 8)
void attn_kernel(const __bf16* __restrict__ Qb, const __bf16* __restrict__ Kb,
                 const __bf16* __restrict__ VTb, float* __restrict__ out)
{
    const int tid  = (int)threadIdx.x;
    const int w    = tid >> 6;
    const int lane = tid & 63;
    const int g  = lane >> 4;
    const int cl = lane & 15;

    // XCD-batch swizzle: HW assigns block n -> XCD n%8. Make batch a function
    // of bid&7 so each XCD touches exactly one batch.
    const int bid = (int)blockIdx.x;
    const int x8  = bid & 7;
    const int b   = x8 & 3;
    const int qt  = ((x8 >> 2) << 7) | (bid >> 3);   // in [0, 256)
    const int qbase = qt * 16;

    const __bf16* Qp = Qb  + ((long)b * SEQ + qbase) * DIM;
    const __bf16* Kp = Kb  + (long)b * SEQ * DIM;
    const __bf16* Vp = VTb + (long)b * DIM * SEQ;

    // Q fragments (held whole kernel): elem e -> Q[qbase+cl][32h+8g+e]
    bf16x8 qf[2];
    qf[0] = *reinterpret_cast<const bf16x8*>(Qp + cl*DIM + 8*g);
    qf[1] = *reinterpret_cast<const bf16x8*>(Qp + cl*DIM + 32 + 8*g);

    f32x4 acc[4];
#pragma unroll
    for (int nt = 0; nt < 4; ++nt) acc[nt] = (f32x4){0.f, 0.f, 0.f, 0.f};
    float mrun = -INFINITY;
    float lsum = 0.f;

    const int k0 = w * (SEQ / 8);
#pragma unroll 1
    for (int kb = k0; kb < k0 + SEQ/8; kb += 64) {
        // ---- scores: S^T tiles via mfma(K, Q) ----
        f32x4 s[4];
#pragma unroll
        for (int kt = 0; kt < 4; ++kt) {
            const __bf16* kp = Kp + (long)(kb + kt*16 + cl) * DIM + 8*g;
            bf16x8 kf0 = *reinterpret_cast<const bf16x8*>(kp);
            bf16x8 kf1 = *reinterpret_cast<const bf16x8*>(kp + 32);
            f32x4 z = (f32x4){0.f, 0.f, 0.f, 0.f};
            z = __builtin_amdgcn_mfma_f32_16x16x32_bf16(kf0, qf[0], z, 0, 0, 0);
            z = __builtin_amdgcn_mfma_f32_16x16x32_bf16(kf1, qf[1], z, 0, 0, 0);
            s[kt] = z;   // s[kt][r] = score(q=cl, k = kb + kt*16 + 4g + r), pre-scaled
        }

        // ---- online softmax for q-row cl ----
        float tmax = s[0][0];
#pragma unroll
        for (int kt = 0; kt < 4; ++kt)
#pragma unroll
            for (int r = 0; r < 4; ++r) tmax = fmaxf(tmax, s[kt][r]);
        tmax = fmaxf(tmax, __shfl_xor(tmax, 16));
        tmax = fmaxf(tmax, __shfl_xor(tmax, 32));

        const float mnew = fmaxf(mrun, tmax);
        const float corr = __expf(mrun - mnew);   // first iter: exp(-inf)=0
        float psum = 0.f;
#pragma unroll
        for (int kt = 0; kt < 4; ++kt)
#pragma unroll
            for (int r = 0; r < 4; ++r) {
                const float p = __expf(s[kt][r] - mnew);
                s[kt][r] = p;
                psum += p;
            }
        psum += __shfl_xor(psum, 16);
        psum += __shfl_xor(psum, 32);
        lsum = lsum * corr + psum;
        mrun = mnew;

        // rescale accumulators: acc row = 4g+r, its corr lives in lane 4g+r
#pragma unroll
        for (int r = 0; r < 4; ++r) {
            const float cr = __shfl(corr, 4*g + r);
#pragma unroll
            for (int nt = 0; nt < 4; ++nt) acc[nt][r] *= cr;
        }

        // ---- pack P: pa0[e] = P[cl][kb + 16*(e>>2) + 4g + (e&3)], pa1: +32
        bf16x8 pa0, pa1;
#pragma unroll
        for (int e = 0; e < 8; ++e) {
            pa0[e] = (__bf16)s[(e >> 2)][e & 3];
            pa1[e] = (__bf16)s[2 + (e >> 2)][e & 3];
        }

        // ---- PV: V-frags are single 16B loads (k-permuted VT), same pattern
#pragma unroll
        for (int nt = 0; nt < 4; ++nt) {
            const __bf16* vp = Vp + (long)(nt*16 + cl) * SEQ + kb;
            bf16x8 vf0 = *reinterpret_cast<const bf16x8*>(vp + 8*g);
            bf16x8 vf1 = *reinterpret_cast<const bf16x8*>(vp + 32 + 8*g);
            acc[nt] = __builtin_amdgcn_mfma_f32_16x16x32_bf16(pa0, vf0, acc[nt], 0, 0, 0);
            acc[nt] = __builtin_amdgcn_mfma_f32_16x16x32_bf16(pa1, vf1, acc[nt], 0, 0, 0);
        }
    }

    // ---- merge the 8 per-wave partials through LDS ----
    __shared__ float lm[8][16];
    __shared__ float ll[8][16];
    __shared__ float lacc[8][16][65];   // +1 pad

    if (lane < 16) { lm[w][lane] = mrun; ll[w][lane] = lsum; }
#pragma unroll
    for (int nt = 0; nt < 4; ++nt)
#pragma unroll
        for (int r = 0; r < 4; ++r)
            lacc[w][4*g + r][nt*16 + cl] = acc[nt][r];
    __syncthreads();

    // combine: thread t -> col c = t&63, rows (t>>6)*2 .. +1
    const int c  = tid & 63;
    const int r0 = (tid >> 6) * 2;
#pragma unroll
    for (int rr = 0; rr < 2; ++rr) {
        const int r = r0 + rr;
        float M = lm[0][r];
#pragma unroll
        for (int j = 1; j < 8; ++j) M = fmaxf(M, lm[j][r]);
        float L = 0.f, v = 0.f;
#pragma unroll
        for (int j = 0; j < 8; ++j) {
            const float f = __expf(lm[j][r] - M);
            L += ll[j][r] * f;
            v += lacc[j][r][c] * f;
        }
        out[((long)b * SEQ + qbase + r) * DIM + c] = v / L;
    }
}

// ---------------------------------------------------------------------------
extern "C" void kernel_launch(void* const* d_in, const int* in_sizes, int n_in,
                              void* d_out, int out_size, void* d_ws, size_t ws_size,
                              hipStream_t stream)
{
    const float* x = (const float*)d_in[0];
    const float* w = (const float*)d_in[1];
    float* out = (float*)d_out;

    char* ws = (char*)d_ws;
    const size_t sz = (size_t)NB * SEQ * DIM * sizeof(__bf16);  // 2 MiB each
    __bf16* Qb  = (__bf16*)(ws);
    __bf16* Kb  = (__bf16*)(ws + sz);
    __bf16* VTb = (__bf16*)(ws + 2 * sz);
    __bf16* WT  = (__bf16*)(ws + 3 * sz);   // 24 KiB

    wprep_kernel<<<3 * DIM * DIM / 256, 256, 0, stream>>>(w, WT);

    dim3 gp(NB * SEQ / 16, 3);
    qkv_prep_kernel<<<gp, 64, 0, stream>>>(x, WT, Qb, Kb, VTb);

    attn_kernel<<<NB * SEQ / 16, 512, 0, stream>>>(Qb, Kb, VTb, out);
}

// Round 5
// 63.201 us; speedup vs baseline: 2.1925x; 2.1925x over previous
//
#include <hip/hip_runtime.h>
#include <hip/hip_bf16.h>
#include <math.h>

using bf16x8 = __attribute__((ext_vector_type(8))) __bf16;
using bf16x4 = __attribute__((ext_vector_type(4))) __bf16;
using f32x4  = __attribute__((ext_vector_type(4))) float;

static constexpr int SEQ = 4096;
static constexpr int DIM = 64;
static constexpr int NB  = 4;

__device__ __forceinline__ void gload16(const void* g, void* l) {
    __builtin_amdgcn_global_load_lds(
        (const __attribute__((address_space(1))) unsigned int*)g,
        (__attribute__((address_space(3))) unsigned int*)l,
        16, 0, 0);
}

// ---------------------------------------------------------------------------
// Kernel 0: cast+transpose W -> WT[slot][out][d] bf16.
// ---------------------------------------------------------------------------
__global__ __launch_bounds__(256)
void wprep_kernel(const float* __restrict__ w, __bf16* __restrict__ WT)
{
    const int idx = (int)blockIdx.x * 256 + (int)threadIdx.x;  // < 3*64*64
    const int s = idx >> 12;
    const int o = (idx >> 6) & 63;
    const int d = idx & 63;
    WT[idx] = (__bf16)w[(s * DIM + d) * DIM + o];
}

// ---------------------------------------------------------------------------
// Kernel 1: fused pos-embed + QKV projection (unchanged, verified).
// V stored k-permuted: within each 64-k block, kl = 32h+16b4+4g+r lives at
// pos = 32h+8g+4b4+r => attention V-frags are single 16B loads.
// ---------------------------------------------------------------------------
__global__ __launch_bounds__(64)
void qkv_prep_kernel(const float* __restrict__ x, const __bf16* __restrict__ WT,
                     __bf16* __restrict__ Qb, __bf16* __restrict__ Kb,
                     __bf16* __restrict__ VTb)
{
    const int lane = (int)threadIdx.x;
    const int g  = lane >> 4;
    const int cl = lane & 15;
    const int rowbase = (int)blockIdx.x * 16;   // in [0, B*S)
    const int slot    = (int)blockIdx.y;        // 0=Q 1=K 2=V

    const __bf16* wt = WT + slot * DIM * DIM;
    bf16x8 wf[4][2];
#pragma unroll
    for (int nt = 0; nt < 4; ++nt)
#pragma unroll
        for (int h = 0; h < 2; ++h)
            wf[nt][h] = *reinterpret_cast<const bf16x8*>(wt + (nt*16 + cl) * DIM + 32*h + 8*g);

    const int row  = rowbase + cl;
    const int spos = row & (SEQ - 1);
    bf16x8 xa[2];
#pragma unroll
    for (int h = 0; h < 2; ++h) {
        const float* xp = x + (long)row * DIM + 32*h + 8*g;
        f32x4 x0 = *reinterpret_cast<const f32x4*>(xp);
        f32x4 x1 = *reinterpret_cast<const f32x4*>(xp + 4);
        bf16x8 v;
#pragma unroll
        for (int e = 0; e < 8; ++e) {
            const int c = 32*h + 8*g + e;
            const float invf = exp2f(-13.287712379549449f * ((float)c * 0.03125f));
            const float pe   = __sinf((float)spos * invf);
            const float xv   = (e < 4) ? x0[e] : x1[e - 4];
            v[e] = (__bf16)(xv + pe);
        }
        xa[h] = v;
    }

    f32x4 acc[4];
#pragma unroll
    for (int nt = 0; nt < 4; ++nt) acc[nt] = (f32x4){0.f, 0.f, 0.f, 0.f};
#pragma unroll
    for (int nt = 0; nt < 4; ++nt) {
        acc[nt] = __builtin_amdgcn_mfma_f32_16x16x32_bf16(xa[0], wf[nt][0], acc[nt], 0, 0, 0);
        acc[nt] = __builtin_amdgcn_mfma_f32_16x16x32_bf16(xa[1], wf[nt][1], acc[nt], 0, 0, 0);
    }

    if (slot < 2) {
        __bf16* dst = (slot == 0) ? Qb : Kb;
        const float scale = (slot == 0) ? 0.125f : 1.0f;
#pragma unroll
        for (int nt = 0; nt < 4; ++nt)
#pragma unroll
            for (int r = 0; r < 4; ++r) {
                const int ro = rowbase + 4*g + r;
                dst[(long)ro * DIM + nt*16 + cl] = (__bf16)(acc[nt][r] * scale);
            }
    } else {
        const int bi   = rowbase >> 12;
        const int sp   = rowbase & (SEQ - 1);
        const int kblk = sp & ~63;
        const int pos0 = 32 * ((rowbase >> 5) & 1) + 8*g + 4 * ((rowbase >> 4) & 1);
#pragma unroll
        for (int nt = 0; nt < 4; ++nt) {
            bf16x4 pk;
#pragma unroll
            for (int r = 0; r < 4; ++r) pk[r] = (__bf16)acc[nt][r];
            *reinterpret_cast<bf16x4*>(VTb + ((long)bi*DIM + nt*16 + cl) * SEQ + kblk + pos0) = pk;
        }
    }
}

// ---------------------------------------------------------------------------
// Kernel 2: flash attention, LDS-staged shared K/V.
// Block = 8 waves (512 thr): wq = w&3 picks the 16-q sub-tile (block owns 64
// q-rows), wk = w>>2 picks the k-half (2-way split-K, pairwise merge).
// Per 64-k chunk, the block stages K+V for BOTH halves (32 KB) once via
// global_load_lds (4 inst/thread), double-buffered, 2-phase schedule.
// LDS 16B-chunks XOR-swizzled by (row&7): inverse-swizzled GLOBAL source +
// swizzled ds_read address (linear LDS dest, rule: both-sides-or-neither).
// grid = 256 blocks = NB * SEQ/64 (1 block/CU), XCD-batch swizzle b=f(bid&7).
// ---------------------------------------------------------------------------
__global__ __launch_bounds__(512)
void attn_kernel(const __bf16* __restrict__ Qb, const __bf16* __restrict__ Kb,
                 const __bf16* __restrict__ VTb, float* __restrict__ out)
{
    __shared__ __bf16 sK[2][2][64][64];   // [buf][half][row][col-chunk swz]
    __shared__ __bf16 sV[2][2][64][64];

    const int tid  = (int)threadIdx.x;
    const int w    = tid >> 6;
    const int lane = tid & 63;
    const int g  = lane >> 4;
    const int cl = lane & 15;
    const int wq = w & 3;
    const int wk = w >> 2;

    const int bid = (int)blockIdx.x;
    const int x8  = bid & 7;
    const int b   = x8 & 3;
    const int qt  = ((x8 >> 2) << 5) | (bid >> 3);   // [0,64), bijective over 256 blocks
    const int qbase = qt * 64;

    const __bf16* Qp = Qb  + ((long)b * SEQ + qbase + wq*16) * DIM;
    const __bf16* Kp = Kb  + (long)b * SEQ * DIM;
    const __bf16* Vp = VTb + (long)b * DIM * SEQ;

    // staging sources for thread tid: row sr, swizzled 16B chunk
    const int sr  = tid >> 3;                        // 0..63
    const int scz = ((tid & 7) ^ (sr & 7)) * 8;      // element offset in row
    const __bf16* srcK0 = Kp + (long)(sr)        * DIM + scz;
    const __bf16* srcK1 = Kp + (long)(2048 + sr) * DIM + scz;
    const __bf16* srcV0 = Vp + (long)sr * SEQ + scz;
    const __bf16* srcV1 = Vp + (long)sr * SEQ + 2048 + scz;

    // Q fragments (held whole kernel)
    bf16x8 qf[2];
    qf[0] = *reinterpret_cast<const bf16x8*>(Qp + cl*DIM + 8*g);
    qf[1] = *reinterpret_cast<const bf16x8*>(Qp + cl*DIM + 32 + 8*g);

    f32x4 acc[4];
#pragma unroll
    for (int nt = 0; nt < 4; ++nt) acc[nt] = (f32x4){0.f, 0.f, 0.f, 0.f};
    float mrun = -INFINITY;
    float lsum = 0.f;

    // swizzled in-row byte offsets for fragment reads (row&7 == cl&7)
    const int swz0 = (( g      ^ (cl & 7)) << 4);
    const int swz1 = (((g + 4) ^ (cl & 7)) << 4);

    // prologue: stage chunk 0
    {
        gload16(srcK0, &sK[0][0][0][0] + tid*8);
        gload16(srcK1, &sK[0][1][0][0] + tid*8);
        gload16(srcV0, &sV[0][0][0][0] + tid*8);
        gload16(srcV1, &sV[0][1][0][0] + tid*8);
    }
    __syncthreads();

    int buf = 0;
#pragma unroll 1
    for (int n = 0; n < 32; ++n) {
        // issue next-chunk staging early (overlaps with compute below)
        if (n < 31) {
            const long ko = (long)(n + 1) * 64;
            gload16(srcK0 + ko*DIM, &sK[buf^1][0][0][0] + tid*8);
            gload16(srcK1 + ko*DIM, &sK[buf^1][1][0][0] + tid*8);
            gload16(srcV0 + ko,     &sV[buf^1][0][0][0] + tid*8);
            gload16(srcV1 + ko,     &sV[buf^1][1][0][0] + tid*8);
        }

        const char* Kl = (const char*)&sK[buf][wk][0][0];
        const char* Vl = (const char*)&sV[buf][wk][0][0];

        // ---- scores: S^T tiles via mfma(K, Q) ----
        f32x4 s[4];
#pragma unroll
        for (int kt = 0; kt < 4; ++kt) {
            const int row = kt*16 + cl;
            bf16x8 kf0 = *reinterpret_cast<const bf16x8*>(Kl + row*128 + swz0);
            bf16x8 kf1 = *reinterpret_cast<const bf16x8*>(Kl + row*128 + swz1);
            f32x4 z = (f32x4){0.f, 0.f, 0.f, 0.f};
            z = __builtin_amdgcn_mfma_f32_16x16x32_bf16(kf0, qf[0], z, 0, 0, 0);
            z = __builtin_amdgcn_mfma_f32_16x16x32_bf16(kf1, qf[1], z, 0, 0, 0);
            s[kt] = z;   // s[kt][r] = score(q=cl, k = chunk*64 + kt*16 + 4g + r)
        }

        // ---- online softmax for q-row cl ----
        float tmax = s[0][0];
#pragma unroll
        for (int kt = 0; kt < 4; ++kt)
#pragma unroll
            for (int r = 0; r < 4; ++r) tmax = fmaxf(tmax, s[kt][r]);
        tmax = fmaxf(tmax, __shfl_xor(tmax, 16));
        tmax = fmaxf(tmax, __shfl_xor(tmax, 32));

        const float mnew = fmaxf(mrun, tmax);
        const float corr = __expf(mrun - mnew);
        float psum = 0.f;
#pragma unroll
        for (int kt = 0; kt < 4; ++kt)
#pragma unroll
            for (int r = 0; r < 4; ++r) {
                const float p = __expf(s[kt][r] - mnew);
                s[kt][r] = p;
                psum += p;
            }
        psum += __shfl_xor(psum, 16);
        psum += __shfl_xor(psum, 32);
        lsum = lsum * corr + psum;
        mrun = mnew;

#pragma unroll
        for (int r = 0; r < 4; ++r) {
            const float cr = __shfl(corr, 4*g + r);
#pragma unroll
            for (int nt = 0; nt < 4; ++nt) acc[nt][r] *= cr;
        }

        // ---- pack P ----
        bf16x8 pa0, pa1;
#pragma unroll
        for (int e = 0; e < 8; ++e) {
            pa0[e] = (__bf16)s[(e >> 2)][e & 3];
            pa1[e] = (__bf16)s[2 + (e >> 2)][e & 3];
        }

        // ---- PV ----
#pragma unroll
        for (int nt = 0; nt < 4; ++nt) {
            const int row = nt*16 + cl;
            bf16x8 vf0 = *reinterpret_cast<const bf16x8*>(Vl + row*128 + swz0);
            bf16x8 vf1 = *reinterpret_cast<const bf16x8*>(Vl + row*128 + swz1);
            acc[nt] = __builtin_amdgcn_mfma_f32_16x16x32_bf16(pa0, vf0, acc[nt], 0, 0, 0);
            acc[nt] = __builtin_amdgcn_mfma_f32_16x16x32_bf16(pa1, vf1, acc[nt], 0, 0, 0);
        }

        __syncthreads();
        buf ^= 1;
    }

    // ---- pairwise split-K merge (wk=1 publishes, wk=0 combines) ----
    // merge arrays alias the (now dead) staging buffers: total LDS stays 64KB
    float (*lacc4)[16][65] = (float (*)[16][65])(&sK[0][0][0][0]);  // 16.6KB
    float* lmf = (float*)&sV[0][0][0][0];        // [4][16]
    float* llf = lmf + 64;                        // [4][16]

    if (wk == 1) {
        if (lane < 16) { lmf[wq*16 + lane] = mrun; llf[wq*16 + lane] = lsum; }
#pragma unroll
        for (int nt = 0; nt < 4; ++nt)
#pragma unroll
            for (int r = 0; r < 4; ++r)
                lacc4[wq][4*g + r][nt*16 + cl] = acc[nt][r];
    }
    __syncthreads();

    if (wk == 0) {
#pragma unroll
        for (int r = 0; r < 4; ++r) {
            const int ro = 4*g + r;
            const float mo = __shfl(mrun, ro);
            const float lo = __shfl(lsum, ro);
            const float mp = lmf[wq*16 + ro];
            const float lp = llf[wq*16 + ro];
            const float M  = fmaxf(mo, mp);
            const float fo = __expf(mo - M);
            const float fp = __expf(mp - M);
            const float inv = 1.f / (lo*fo + lp*fp);
#pragma unroll
            for (int nt = 0; nt < 4; ++nt) {
                const float val = (acc[nt][r]*fo + lacc4[wq][ro][nt*16 + cl]*fp) * inv;
                out[((long)b * SEQ + qbase + wq*16 + ro) * DIM + nt*16 + cl] = val;
            }
        }
    }
}

// ---------------------------------------------------------------------------
extern "C" void kernel_launch(void* const* d_in, const int* in_sizes, int n_in,
                              void* d_out, int out_size, void* d_ws, size_t ws_size,
                              hipStream_t stream)
{
    const float* x = (const float*)d_in[0];
    const float* w = (const float*)d_in[1];
    float* out = (float*)d_out;

    char* ws = (char*)d_ws;
    const size_t sz = (size_t)NB * SEQ * DIM * sizeof(__bf16);  // 2 MiB each
    __bf16* Qb  = (__bf16*)(ws);
    __bf16* Kb  = (__bf16*)(ws + sz);
    __bf16* VTb = (__bf16*)(ws + 2 * sz);
    __bf16* WT  = (__bf16*)(ws + 3 * sz);   // 24 KiB

    wprep_kernel<<<3 * DIM * DIM / 256, 256, 0, stream>>>(w, WT);

    dim3 gp(NB * SEQ / 16, 3);
    qkv_prep_kernel<<<gp, 64, 0, stream>>>(x, WT, Qb, Kb, VTb);

    // FIX (R3 bug): one block per 64 q-rows per batch -> NB*SEQ/64 = 256 blocks
    attn_kernel<<<NB * SEQ / 64, 512, 0, stream>>>(Qb, Kb, VTb, out);
}

// Round 6
// 56.761 us; speedup vs baseline: 2.4413x; 1.1134x over previous
//
#include <hip/hip_runtime.h>
#include <hip/hip_bf16.h>
#include <math.h>

using bf16x8 = __attribute__((ext_vector_type(8))) __bf16;
using bf16x4 = __attribute__((ext_vector_type(4))) __bf16;
using f32x4  = __attribute__((ext_vector_type(4))) float;

static constexpr int SEQ = 4096;
static constexpr int DIM = 64;
static constexpr int NB  = 4;
// 0.125 (1/sqrt(64)) * log2(e): scores land in log2 domain -> exp2 everywhere
static constexpr float QSCALE = 0.18033688011112042f;

__device__ __forceinline__ void gload16(const void* g, void* l) {
    __builtin_amdgcn_global_load_lds(
        (const __attribute__((address_space(1))) unsigned int*)g,
        (__attribute__((address_space(3))) unsigned int*)l,
        16, 0, 0);
}

__device__ __forceinline__ float fast_exp2(float x) {
#if __has_builtin(__builtin_amdgcn_exp2f)
    return __builtin_amdgcn_exp2f(x);
#else
    return exp2f(x);
#endif
}

// ---------------------------------------------------------------------------
// Kernel 0: cast+transpose W -> WT[slot][out][d] bf16.
// ---------------------------------------------------------------------------
__global__ __launch_bounds__(256)
void wprep_kernel(const float* __restrict__ w, __bf16* __restrict__ WT)
{
    const int idx = (int)blockIdx.x * 256 + (int)threadIdx.x;  // < 3*64*64
    const int s = idx >> 12;
    const int o = (idx >> 6) & 63;
    const int d = idx & 63;
    WT[idx] = (__bf16)w[(s * DIM + d) * DIM + o];
}

// ---------------------------------------------------------------------------
// Kernel 1: fused pos-embed + QKV projection, 3 slots folded into one pass
// (x-load + trig computed ONCE, reused for Q,K,V). Block = 256 thr (4 waves),
// each wave owns 16 rows. grid = B*S/64 = 1024.
// Q pre-scaled by QSCALE (log2 domain). V stored k-permuted: within each
// 64-k block, kl = 32h+16b4+4g+r lives at pos = 32h+8g+4b4+r.
// ---------------------------------------------------------------------------
__global__ __launch_bounds__(256)
void qkv_prep_kernel(const float* __restrict__ x, const __bf16* __restrict__ WT,
                     __bf16* __restrict__ Qb, __bf16* __restrict__ Kb,
                     __bf16* __restrict__ VTb)
{
    const int tid  = (int)threadIdx.x;
    const int lane = tid & 63;
    const int g  = lane >> 4;
    const int cl = lane & 15;
    const int rowbase = (int)blockIdx.x * 64 + (tid >> 6) * 16;  // in [0, B*S)

    // A fragments: x' = x + pos_embed, rounded to bf16. One row per lane (cl).
    const int row  = rowbase + cl;
    const int spos = row & (SEQ - 1);
    bf16x8 xa[2];
#pragma unroll
    for (int h = 0; h < 2; ++h) {
        const float* xp = x + (long)row * DIM + 32*h + 8*g;
        f32x4 x0 = *reinterpret_cast<const f32x4*>(xp);
        f32x4 x1 = *reinterpret_cast<const f32x4*>(xp + 4);
        bf16x8 v;
#pragma unroll
        for (int e = 0; e < 8; ++e) {
            const int c = 32*h + 8*g + e;
            const float invf = exp2f(-13.287712379549449f * ((float)c * 0.03125f));
            const float pe   = __sinf((float)spos * invf);
            const float xv   = (e < 4) ? x0[e] : x1[e - 4];
            v[e] = (__bf16)(xv + pe);
        }
        xa[h] = v;
    }

#pragma unroll
    for (int slot = 0; slot < 3; ++slot) {
        const __bf16* wt = WT + slot * DIM * DIM;
        f32x4 acc[4];
#pragma unroll
        for (int nt = 0; nt < 4; ++nt) acc[nt] = (f32x4){0.f, 0.f, 0.f, 0.f};
#pragma unroll
        for (int nt = 0; nt < 4; ++nt) {
            bf16x8 w0 = *reinterpret_cast<const bf16x8*>(wt + (nt*16 + cl) * DIM + 8*g);
            bf16x8 w1 = *reinterpret_cast<const bf16x8*>(wt + (nt*16 + cl) * DIM + 32 + 8*g);
            acc[nt] = __builtin_amdgcn_mfma_f32_16x16x32_bf16(xa[0], w0, acc[nt], 0, 0, 0);
            acc[nt] = __builtin_amdgcn_mfma_f32_16x16x32_bf16(xa[1], w1, acc[nt], 0, 0, 0);
        }

        // C/D layout (HW-verified): lane l, reg r -> row (l>>4)*4+r, col l&15.
        if (slot < 2) {
            __bf16* dst = (slot == 0) ? Qb : Kb;
            const float scale = (slot == 0) ? QSCALE : 1.0f;
#pragma unroll
            for (int nt = 0; nt < 4; ++nt)
#pragma unroll
                for (int r = 0; r < 4; ++r) {
                    const int ro = rowbase + 4*g + r;
                    dst[(long)ro * DIM + nt*16 + cl] = (__bf16)(acc[nt][r] * scale);
                }
        } else {
            const int bi   = rowbase >> 12;
            const int sp   = rowbase & (SEQ - 1);
            const int kblk = sp & ~63;
            const int pos0 = 32 * ((rowbase >> 5) & 1) + 8*g + 4 * ((rowbase >> 4) & 1);
#pragma unroll
            for (int nt = 0; nt < 4; ++nt) {
                bf16x4 pk;
#pragma unroll
                for (int r = 0; r < 4; ++r) pk[r] = (__bf16)acc[nt][r];
                *reinterpret_cast<bf16x4*>(VTb + ((long)bi*DIM + nt*16 + cl) * SEQ + kblk + pos0) = pk;
            }
        }
    }
}

// ---------------------------------------------------------------------------
// Kernel 2: flash attention, 16 waves/block (1024 thr), 4-way split-K.
// wq = w&3 picks the 16-q sub-tile (block owns 64 q-rows); wk = w>>2 picks
// the k-quarter, processed in 32-k chunks (32 iters). Per iter the block
// stages 4x(4KB K + 4KB V) = 32KB via global_load_lds, double-buffered.
// K chunk LDS [32][64]: 16B chunks XOR-swizzled by (row&7).
// V chunk LDS [64][32]: 16B chunks XOR-swizzled by ((drow>>1)&3).
// (linear LDS dest + inverse-swizzled global source + swizzled read addr)
// grid = 256 (1 block/CU), XCD-batch swizzle b=f(bid&7). Softmax in log2
// domain (exp2), defer-max skip when chunk max doesn't raise the running max.
// 4-way split-K merge through LDS (aliased onto dead staging buffers).
// ---------------------------------------------------------------------------
__global__ __launch_bounds__(1024)
void attn_kernel(const __bf16* __restrict__ Qb, const __bf16* __restrict__ Kb,
                 const __bf16* __restrict__ VTb, float* __restrict__ out)
{
    __shared__ char smem[65536];
    __bf16* sK = (__bf16*)smem;              // [2][4][32][64]: buf*8192+wk*2048+row*64+col
    __bf16* sV = (__bf16*)(smem + 32768);    // [2][4][64][32]: buf*8192+wk*2048+drow*32+col

    const int tid  = (int)threadIdx.x;
    const int w    = tid >> 6;
    const int lane = tid & 63;
    const int g  = lane >> 4;
    const int cl = lane & 15;
    const int wq = w & 3;
    const int wk = w >> 2;

    const int bid = (int)blockIdx.x;
    const int x8  = bid & 7;
    const int b   = x8 & 3;
    const int qt  = ((x8 >> 2) << 5) | (bid >> 3);   // [0,64), bijective over 256 blocks
    const int qbase = qt * 64;

    const __bf16* Qp = Qb  + ((long)b * SEQ + qbase + wq*16) * DIM;
    const __bf16* Kp = Kb  + (long)b * SEQ * DIM;
    const __bf16* Vp = VTb + (long)b * DIM * SEQ;

    // staging: thread stages one 16B K slot and one 16B V slot per iter
    const int ws_ = tid >> 8;                  // staged wk quarter 0..3
    const int ksr = (tid >> 3) & 31;           // K row within chunk
    const int kc  = tid & 7;
    const int kcs = kc ^ (ksr & 7);            // inverse-swizzled source chunk
    const __bf16* srcK = Kp + (long)(ws_*1024 + ksr) * DIM + kcs*8;

    const int vdr = (tid >> 2) & 63;           // V d-row
    const int vc  = tid & 3;
    const int vcs = vc ^ ((vdr >> 1) & 3);
    const __bf16* srcV = Vp + (long)vdr * SEQ + ws_*1024 + vcs*8;

    __bf16* dstK = sK + tid*8;                 // + buf*8192
    __bf16* dstV = sV + tid*8;

    // Q fragments (held whole kernel)
    bf16x8 qf0 = *reinterpret_cast<const bf16x8*>(Qp + cl*DIM + 8*g);
    bf16x8 qf1 = *reinterpret_cast<const bf16x8*>(Qp + cl*DIM + 32 + 8*g);

    f32x4 acc[4];
#pragma unroll
    for (int nt = 0; nt < 4; ++nt) acc[nt] = (f32x4){0.f, 0.f, 0.f, 0.f};
    float mrun = -INFINITY;
    float lsum = 0.f;

    // swizzled read offsets
    const int kswz0 = (( g      ^ (cl & 7)) << 4);
    const int kswz1 = (((g + 4) ^ (cl & 7)) << 4);
    const int vswz  = (( g ^ ((cl >> 1) & 3)) << 4);

    // prologue: stage chunk 0
    gload16(srcK, dstK);
    gload16(srcV, dstV);
    __syncthreads();

    int buf = 0;
#pragma unroll 1
    for (int n = 0; n < 32; ++n) {
        if (n < 31) {
            gload16(srcK + (long)(n + 1) * 32 * DIM, dstK + (buf^1)*8192);
            gload16(srcV + (n + 1) * 32,             dstV + (buf^1)*8192);
        }

        const char* Kl = (const char*)(sK + buf*8192 + wk*2048);
        const char* Vl = (const char*)(sV + buf*8192 + wk*2048);

        // ---- scores: S^T tiles via mfma(K, Q), 32 k per iter ----
        f32x4 s[2];
#pragma unroll
        for (int kt = 0; kt < 2; ++kt) {
            const int row = kt*16 + cl;
            bf16x8 kf0 = *reinterpret_cast<const bf16x8*>(Kl + row*128 + kswz0);
            bf16x8 kf1 = *reinterpret_cast<const bf16x8*>(Kl + row*128 + kswz1);
            f32x4 z = (f32x4){0.f, 0.f, 0.f, 0.f};
            z = __builtin_amdgcn_mfma_f32_16x16x32_bf16(kf0, qf0, z, 0, 0, 0);
            z = __builtin_amdgcn_mfma_f32_16x16x32_bf16(kf1, qf1, z, 0, 0, 0);
            s[kt] = z;   // s[kt][r] = score_log2(q=cl, k = kt*16 + 4g + r)
        }

        // ---- online softmax (log2 domain) for q-row cl ----
        float tmax = fmaxf(fmaxf(fmaxf(s[0][0], s[0][1]), fmaxf(s[0][2], s[0][3])),
                           fmaxf(fmaxf(s[1][0], s[1][1]), fmaxf(s[1][2], s[1][3])));
        tmax = fmaxf(tmax, __shfl_xor(tmax, 16));
        tmax = fmaxf(tmax, __shfl_xor(tmax, 32));

        // defer-max: exact skip (THR=0) when no row's max grew
        if (!__all(tmax <= mrun)) {
            const float mnew = fmaxf(mrun, tmax);
            const float corr = fast_exp2(mrun - mnew);   // first iter: exp2(-inf)=0
            lsum *= corr;
#pragma unroll
            for (int r = 0; r < 4; ++r) {
                const float cr = __shfl(corr, 4*g + r);
#pragma unroll
                for (int nt = 0; nt < 4; ++nt) acc[nt][r] *= cr;
            }
            mrun = mnew;
        }

        float psum = 0.f;
#pragma unroll
        for (int kt = 0; kt < 2; ++kt)
#pragma unroll
            for (int r = 0; r < 4; ++r) {
                const float p = fast_exp2(s[kt][r] - mrun);
                s[kt][r] = p;
                psum += p;
            }
        psum += __shfl_xor(psum, 16);
        psum += __shfl_xor(psum, 32);
        lsum += psum;

        // ---- pack P: pa[e] = P[cl][16*(e>>2) + 4g + (e&3)] ----
        bf16x8 pa;
#pragma unroll
        for (int e = 0; e < 8; ++e) pa[e] = (__bf16)s[e >> 2][e & 3];

        // ---- PV: one 16B V-frag + one MFMA per nt (k-permuted VT) ----
#pragma unroll
        for (int nt = 0; nt < 4; ++nt) {
            const int row = nt*16 + cl;
            bf16x8 vf = *reinterpret_cast<const bf16x8*>(Vl + row*64 + vswz);
            acc[nt] = __builtin_amdgcn_mfma_f32_16x16x32_bf16(pa, vf, acc[nt], 0, 0, 0);
        }

        __syncthreads();
        buf ^= 1;
    }

    // ---- 4-way split-K merge through LDS (aliases dead staging buffers) ----
    // lacc: [12][16][65] f32 at smem+0 (49,920B); lm/ll: [12][16] f32 after.
    float* lacc = (float*)smem;
    float* lm   = (float*)(smem + 49920);
    float* ll   = (float*)(smem + 50688);

    if (wk > 0) {
        const int pi = (wk - 1) * 4 + wq;
        if (lane < 16) { lm[pi*16 + lane] = mrun; ll[pi*16 + lane] = lsum; }
#pragma unroll
        for (int nt = 0; nt < 4; ++nt)
#pragma unroll
            for (int r = 0; r < 4; ++r)
                lacc[pi*1040 + (4*g + r)*65 + nt*16 + cl] = acc[nt][r];
    }
    __syncthreads();

    if (wk == 0) {
#pragma unroll
        for (int r = 0; r < 4; ++r) {
            const int ro = 4*g + r;
            const float mo = __shfl(mrun, ro);
            const float lo = __shfl(lsum, ro);
            const float m1 = lm[(wq     )*16 + ro], l1 = ll[(wq     )*16 + ro];
            const float m2 = lm[(4 + wq )*16 + ro], l2 = ll[(4 + wq )*16 + ro];
            const float m3 = lm[(8 + wq )*16 + ro], l3 = ll[(8 + wq )*16 + ro];
            const float M  = fmaxf(fmaxf(mo, m1), fmaxf(m2, m3));
            const float f0 = fast_exp2(mo - M);
            const float f1 = fast_exp2(m1 - M);
            const float f2 = fast_exp2(m2 - M);
            const float f3 = fast_exp2(m3 - M);
            const float inv = 1.f / (lo*f0 + l1*f1 + l2*f2 + l3*f3);
#pragma unroll
            for (int nt = 0; nt < 4; ++nt) {
                const int col = nt*16 + cl;
                const float val = acc[nt][r]*f0
                    + lacc[(wq    )*1040 + ro*65 + col]*f1
                    + lacc[(4 + wq)*1040 + ro*65 + col]*f2
                    + lacc[(8 + wq)*1040 + ro*65 + col]*f3;
                out[((long)b * SEQ + qbase + wq*16 + ro) * DIM + col] = val * inv;
            }
        }
    }
}

// ---------------------------------------------------------------------------
extern "C" void kernel_launch(void* const* d_in, const int* in_sizes, int n_in,
                              void* d_out, int out_size, void* d_ws, size_t ws_size,
                              hipStream_t stream)
{
    const float* x = (const float*)d_in[0];
    const float* w = (const float*)d_in[1];
    float* out = (float*)d_out;

    char* ws = (char*)d_ws;
    const size_t sz = (size_t)NB * SEQ * DIM * sizeof(__bf16);  // 2 MiB each
    __bf16* Qb  = (__bf16*)(ws);
    __bf16* Kb  = (__bf16*)(ws + sz);
    __bf16* VTb = (__bf16*)(ws + 2 * sz);
    __bf16* WT  = (__bf16*)(ws + 3 * sz);   // 24 KiB

    wprep_kernel<<<3 * DIM * DIM / 256, 256, 0, stream>>>(w, WT);

    qkv_prep_kernel<<<NB * SEQ / 64, 256, 0, stream>>>(x, WT, Qb, Kb, VTb);

    attn_kernel<<<NB * SEQ / 64, 1024, 0, stream>>>(Qb, Kb, VTb, out);
}